// Round 12
// baseline (1510.268 us; speedup 1.0000x reference)
//
#include <hip/hip_runtime.h>

// ---------------------------------------------------------------------------
// JointlyTrainModel round 12:
//  - R11 regression post-mortem: bf16 activation storage made cheb's staging
//    path dual-typed (float vs ushort loads) -> more exposed latency in a
//    latency-bound loop. REVERT to R10 numerics (X248 fp32, best measured).
//  - NEW: all 4 cheb layers fused into ONE kernel (the dense-block cascade is
//    per-graph: block g's layer-N+1 input = block g's own layer-N output).
//    __threadfence() between layers (vmcnt drain + L1 inv) for own-block
//    global write->read visibility. Kills 3 device drains + 3 launches + 3
//    tails; T-frags load once.
//  - head1: K=64 stages (R11) with fp32-A + RTNE convert staging (R10 path).
//  - init_bias H1+H2 merged into one launch. Total launches 14 -> 10.
// ---------------------------------------------------------------------------

#define NODES   62
#define BATCH   2048
#define NTOT    (NODES * BATCH)     // 126976
#define IN_DIM  128
#define OUT_DIM 62
#define ACOLS   248                 // 4*62 activation cols
#define FEAT    15376               // 62*248
#define LIN1    512
#define LIN2    256
#define NCLS    3
#define BN_EPS  1e-5f
#define FSTR    36                  // fp32 LDS row stride (floats): 144B rows
#define HSTR    72                  // bf16 LDS row stride in head1 (ushorts)

typedef __attribute__((ext_vector_type(8)))  short  short8;
typedef __attribute__((ext_vector_type(4)))  float  f32x4;
typedef __attribute__((ext_vector_type(16))) float  f32x16;

__device__ inline unsigned short f2bf(float x) {   // RTNE
    unsigned u = __builtin_bit_cast(unsigned, x);
    return (unsigned short)((u + 0x7fffu + ((u >> 16) & 1u)) >> 16);
}
__device__ inline float bf2f(unsigned short h) {
    return __builtin_bit_cast(float, (unsigned)h << 16);
}
// truncation hi/lo split: x ~= hi + lo, |err| ~ 2^-16 |x|
__device__ inline void tsplit(float x, unsigned short& hi, unsigned short& lo) {
    unsigned u = __builtin_bit_cast(unsigned, x);
    hi = (unsigned short)(u >> 16);
    float r = x - __builtin_bit_cast(float, u & 0xffff0000u);
    lo = (unsigned short)(__builtin_bit_cast(unsigned, r) >> 16);
}

// ---------------------------------------------------------------------------
// Build T1 = L~, T2 = 2 L~^2 - I in LDS and emit A-frag-order hi/lo Tf.
// ---------------------------------------------------------------------------
__global__ __launch_bounds__(256) void build_LT_convT(
    const int* __restrict__ ei, int E, int epg, unsigned short* __restrict__ Tf)
{
    __shared__ float Ls[NODES * NODES];
    __shared__ float Ts[2][64 * 64];
    __shared__ int   deg[NODES];
    __shared__ float dinv[NODES];
    const int t = threadIdx.x;
    for (int i = t; i < NODES * NODES; i += 256) Ls[i] = 0.f;
    if (t < NODES) deg[t] = 0;
    __syncthreads();
    const int* row = ei;
    const int* col = ei + E;
    for (int j = t; j < epg; j += 256) atomicAdd(&deg[row[j]], 1);
    __syncthreads();
    if (t < NODES) dinv[t] = (deg[t] > 0) ? rsqrtf((float)deg[t]) : 0.f;
    __syncthreads();
    for (int j = t; j < epg; j += 256) {
        int r = row[j], c = col[j];
        atomicAdd(&Ls[r * NODES + c], -dinv[r] * dinv[c]);
    }
    __syncthreads();
    for (int idx = t; idx < 4096; idx += 256) {
        int r = idx >> 6, c = idx & 63;
        float t1 = 0.f, t2 = 0.f;
        if (r < NODES && c < NODES) {
            t1 = Ls[r * NODES + c];
            float s = 0.f;
            for (int j = 0; j < NODES; ++j) s += Ls[r * NODES + j] * Ls[j * NODES + c];
            t2 = 2.f * s - (r == c ? 1.f : 0.f);
        }
        Ts[0][idx] = t1;
        Ts[1][idx] = t2;
    }
    __syncthreads();
    for (int idx = t; idx < 16384; idx += 256) {
        int j    = idx & 7;
        int lane = (idx >> 3) & 63;
        int pl   = (idx >> 9) & 1;
        int ks   = (idx >> 10) & 3;
        int w    = (idx >> 12) & 3;
        int m = (w & 1) * 32 + (lane & 31);
        int k = ks * 16 + (lane >> 5) * 8 + j;
        float v = Ts[w >> 1][m * 64 + k];
        unsigned short hi, lo;
        tsplit(v, hi, lo);
        Tf[idx] = pl ? lo : hi;
    }
}

// H1 = bh1 broadcast, H2 = bh2 broadcast, one launch.
__global__ __launch_bounds__(256) void init_bias2(
    float* __restrict__ H1, const float* __restrict__ bh1,
    float* __restrict__ H2, const float* __restrict__ bh2)
{
    int i = blockIdx.x * 256 + threadIdx.x;
    const int n1 = BATCH * LIN1 / 4;              // 262144
    if (i < n1) {
        ((float4*)H1)[i] = ((const float4*)bh1)[i & (LIN1 / 4 - 1)];
    } else {
        int j = i - n1;                           // < BATCH*LIN2/4
        ((float4*)H2)[j] = ((const float4*)bh2)[j & (LIN2 / 4 - 1)];
    }
}

// ---------------------------------------------------------------------------
// All 4 cheb weight tensors -> 32x32x16 B-fragment order hi/lo, one launch.
// Outputs are contiguous in ws: chunk-cumulative offsets {0,4,10,18}*12288.
// ---------------------------------------------------------------------------
__global__ __launch_bounds__(256) void conv_wcheb_all(
    const float* __restrict__ W1, const float* __restrict__ W2,
    const float* __restrict__ W3, const float* __restrict__ W4,
    unsigned short* __restrict__ WTall)
{
    const int layer = blockIdx.y;
    const float* W = (layer == 0) ? W1 : (layer == 1) ? W2 : (layer == 2) ? W3 : W4;
    const int d    = (layer == 0) ? 128 : (layer == 1) ? 190 : (layer == 2) ? 252 : 314;
    const int dpad = (layer == 0) ? 128 : (layer == 1) ? 192 : (layer == 2) ? 256 : 320;
    const int cum  = (layer == 0) ? 0 : (layer == 1) ? 4 : (layer == 2) ? 10 : 18;
    unsigned short* WTf = WTall + (size_t)cum * 12288;
    const int total = (dpad >> 5) * 12288;
    int idx = blockIdx.x * 256 + threadIdx.x;
    if (idx >= total) return;
    int j    = idx & 7;
    int lane = (idx >> 3) & 63;
    int f    = idx >> 9;
    int nt   = f & 1;
    int pl   = (f >> 1) & 1;
    int ks   = (f >> 2) & 1;
    int seg  = (f >> 3) % 3;
    int ch   = (f >> 3) / 3;
    int n  = nt * 32 + (lane & 31);
    int kk = ch * 32 + ks * 16 + (lane >> 5) * 8 + j;
    float v = (n < NODES && kk < d) ? W[((size_t)seg * d + kk) * OUT_DIM + n] : 0.f;
    unsigned short hi, lo;
    tsplit(v, hi, lo);
    WTf[idx] = pl ? lo : hi;
}

// ---------------------------------------------------------------------------
// Wh1 [15376][512] fp32 -> Wh1T [512][15376] bf16 via LDS 32x32 transpose.
// ---------------------------------------------------------------------------
__global__ __launch_bounds__(256) void transpose_wh1(
    const float* __restrict__ W, unsigned short* __restrict__ WT)
{
    __shared__ float T[32][33];
    const int k0 = blockIdx.x * 32, n0 = blockIdx.y * 32;
    {
        int kl = threadIdx.x >> 3, n4 = (threadIdx.x & 7) * 4;
        if (k0 + kl < FEAT) {
            float4 v = *(const float4*)&W[(size_t)(k0 + kl) * LIN1 + n0 + n4];
            T[kl][n4] = v.x; T[kl][n4 + 1] = v.y; T[kl][n4 + 2] = v.z; T[kl][n4 + 3] = v.w;
        }
    }
    __syncthreads();
    {
        int nl = threadIdx.x >> 3, k4 = (threadIdx.x & 7) * 4;
        if (k0 + k4 + 3 < FEAT) {
            ushort4 o;
            o.x = f2bf(T[k4 + 0][nl]);
            o.y = f2bf(T[k4 + 1][nl]);
            o.z = f2bf(T[k4 + 2][nl]);
            o.w = f2bf(T[k4 + 3][nl]);
            *(ushort4*)&WT[(size_t)(n0 + nl) * FEAT + k0 + k4] = o;
        }
    }
}

// ---------------------------------------------------------------------------
// FUSED 4-layer Cheb cascade. Block = one graph for ALL layers (cascade is
// per-graph). Per layer: R10's 3-barrier chunk loop; epilogue -> X248;
// __threadfence() (vmcnt drain + L1 inv) before next layer reads own writes.
// ---------------------------------------------------------------------------
__global__ __launch_bounds__(256, 2) void cheb_fused(
    const float* __restrict__ x, float* __restrict__ X248,
    const unsigned short* __restrict__ WTall, const unsigned short* __restrict__ Tf,
    const float* __restrict__ b1, const float* __restrict__ b2,
    const float* __restrict__ b3, const float* __restrict__ b4)
{
    __shared__ __align__(16) float hr [64 * FSTR];
    __shared__ __align__(16) float t1r[64 * FSTR];
    __shared__ __align__(16) float t2r[64 * FSTR];
    __shared__ __align__(16) unsigned short hBf[8 * 512];    //  8 KB
    __shared__ __align__(16) unsigned short Bs[24 * 512];    // 24 KB
    __shared__ float bias_s[64];

    const int tid  = threadIdx.x;
    const int g    = blockIdx.x;
    const int lane = tid & 63;
    const int wv   = tid >> 6;

    // permanent T-fragments (loaded ONCE for all 4 layers)
    short8 Tfr[4][2];
    #pragma unroll
    for (int ks = 0; ks < 4; ++ks)
        #pragma unroll
        for (int pl = 0; pl < 2; ++pl)
            Tfr[ks][pl] = *(const short8*)(Tf + (((size_t)(wv * 4 + ks) * 2 + pl) << 9) + lane * 8);

    const int fcol = tid & 31, rblk = tid >> 5;   // staging map
    const int kst = rblk >> 1, lh = rblk & 1;     // hBf target
    const int mtw = wv >> 1, ntw = wv & 1;        // ph4/epilogue tile

    const int dtab[4]    = {128, 190, 252, 314};
    const int dpadtab[4] = {128, 192, 256, 320};
    const int cumtab[4]  = {0, 4, 10, 18};

#define LOADCH(cn)                                                             \
    do {                                                                       \
        const int gf_ = (cn) * 32 + fcol;                                      \
        const bool fromx_ = ((cn) * 32 < IN_DIM);                              \
        _Pragma("unroll")                                                      \
        for (int p = 0; p < 8; ++p) {                                          \
            int r_ = rblk * 8 + p;                                             \
            float v_ = 0.f;                                                    \
            if (r_ < NODES && gf_ < d)                                         \
                v_ = fromx_ ? x[(size_t)(g * NODES + r_) * IN_DIM + gf_]       \
                            : X248[(size_t)(g * NODES + r_) * ACOLS + (gf_ - IN_DIM)]; \
            vh[p] = v_;                                                        \
        }                                                                      \
        const short8* wsrc_ = (const short8*)(wtf + (size_t)(cn) * 12288);     \
        _Pragma("unroll")                                                      \
        for (int i = 0; i < 6; ++i) breg[i] = wsrc_[i * 256 + tid];            \
    } while (0)

    float  vh[8];
    short8 breg[6];

    for (int layer = 0; layer < 4; ++layer) {
        const int d    = dtab[layer];
        const int dpad = dpadtab[layer];
        const int nchunk = dpad >> 5;
        const unsigned short* wtf = WTall + (size_t)cumtab[layer] * 12288;
        const float* bias = (layer == 0) ? b1 : (layer == 1) ? b2
                          : (layer == 2) ? b3 : b4;

        __syncthreads();   // prev epilogue done before bias_s overwrite
        if (layer > 0) __threadfence();   // own X248 writes -> visible (L1 inv)
        if (tid < 64) bias_s[tid] = (tid < OUT_DIM) ? bias[tid] : 0.f;

        f32x16 acc;
        #pragma unroll
        for (int i = 0; i < 16; ++i) acc[i] = 0.f;

        LOADCH(0);   // prologue (chunk 0 reads x only)

        for (int ch = 0; ch < nchunk; ++ch) {
            // ---- ph1: write staged data from registers
            {
                short8 hi8, lo8;
                #pragma unroll
                for (int p = 0; p < 8; ++p) {
                    unsigned short h_, l_;
                    tsplit(vh[p], h_, l_);
                    hi8[p] = (short)h_; lo8[p] = (short)l_;
                    hr[(rblk * 8 + p) * FSTR + fcol] = vh[p];
                }
                const int dlane = lh * 32 + fcol;
                *(short8*)&hBf[((kst * 2 + 0) << 9) + dlane * 8] = hi8;
                *(short8*)&hBf[((kst * 2 + 1) << 9) + dlane * 8] = lo8;
                #pragma unroll
                for (int i = 0; i < 6; ++i) ((short8*)Bs)[i * 256 + tid] = breg[i];
            }
            __syncthreads();   // A
            // ---- ph3: P = T@h
            {
                f32x16 pacc;
                #pragma unroll
                for (int i = 0; i < 16; ++i) pacc[i] = 0.f;
                #pragma unroll
                for (int ks = 0; ks < 4; ++ks) {
                    short8 bhi = *(const short8*)&hBf[((ks * 2 + 0) << 9) + lane * 8];
                    short8 blo = *(const short8*)&hBf[((ks * 2 + 1) << 9) + lane * 8];
                    pacc = __builtin_amdgcn_mfma_f32_32x32x16_bf16(Tfr[ks][0], bhi, pacc, 0, 0, 0);
                    pacc = __builtin_amdgcn_mfma_f32_32x32x16_bf16(Tfr[ks][0], blo, pacc, 0, 0, 0);
                    pacc = __builtin_amdgcn_mfma_f32_32x32x16_bf16(Tfr[ks][1], bhi, pacc, 0, 0, 0);
                }
                float* dst = (wv < 2) ? t1r : t2r;
                const int mbase = (wv & 1) * 32 + 4 * (lane >> 5);
                const int ccol  = lane & 31;
                #pragma unroll
                for (int reg = 0; reg < 16; ++reg) {
                    int rr = mbase + (reg & 3) + 8 * (reg >> 2);
                    dst[rr * FSTR + ccol] = pacc[reg];
                }
            }
            __syncthreads();   // B
            // ---- ph4: issue next-chunk loads (drain at barrier C), then MFMA
            {
                if (ch + 1 < nchunk) LOADCH(ch + 1);
                #pragma unroll
                for (int seg = 0; seg < 3; ++seg) {
                    const float* src = (seg == 0) ? hr : (seg == 1) ? t1r : t2r;
                    #pragma unroll
                    for (int ks = 0; ks < 2; ++ks) {
                        const int kf = ks * 16 + (lane >> 5) * 8;
                        const float* ap = &src[(mtw * 32 + (lane & 31)) * FSTR + kf];
                        f32x4 u0 = *(const f32x4*)ap;
                        f32x4 u1 = *(const f32x4*)(ap + 4);
                        short8 ahi, alo;
                        #pragma unroll
                        for (int j = 0; j < 4; ++j) {
                            unsigned short h_, l_;
                            tsplit(u0[j], h_, l_); ahi[j] = (short)h_; alo[j] = (short)l_;
                            tsplit(u1[j], h_, l_); ahi[4 + j] = (short)h_; alo[4 + j] = (short)l_;
                        }
                        const unsigned short* bp =
                            Bs + ((((seg * 2 + ks) * 2 + 0) * 2 + ntw) << 9) + lane * 8;
                        short8 bhi = *(const short8*)bp;
                        short8 blo = *(const short8*)(bp + 1024);
                        acc = __builtin_amdgcn_mfma_f32_32x32x16_bf16(ahi, bhi, acc, 0, 0, 0);
                        acc = __builtin_amdgcn_mfma_f32_32x32x16_bf16(ahi, blo, acc, 0, 0, 0);
                        acc = __builtin_amdgcn_mfma_f32_32x32x16_bf16(alo, bhi, acc, 0, 0, 0);
                    }
                }
            }
            __syncthreads();   // C
        }
        // epilogue: relu(acc + bias) -> X248[:, (d-128) .. (d-128)+62)
        {
            const int c = ntw * 32 + (lane & 31);
            if (c < OUT_DIM) {
                const int mbase = mtw * 32 + 4 * (lane >> 5);
                #pragma unroll
                for (int reg = 0; reg < 16; ++reg) {
                    int m = mbase + (reg & 3) + 8 * (reg >> 2);
                    if (m < NODES) {
                        float v = fmaxf(acc[reg] + bias_s[c], 0.f);
                        X248[(size_t)(g * NODES + m) * ACOLS + (d - IN_DIM) + c] = v;
                    }
                }
            }
        }
    }
#undef LOADCH
}

// ---------------------------------------------------------------------------
// Head GEMM1, bf16 MFMA, 64x128 tile, K=64 stages, split-K=8, pipelined.
// A from X248 fp32 (RTNE convert in registers), B from Wh1T bf16.
// ---------------------------------------------------------------------------
#define SPLIT1 8
__global__ __launch_bounds__(256) void gemm_head1_mfma(
    const float* __restrict__ F32, const unsigned short* __restrict__ WT1,
    float* __restrict__ H1)
{
    __shared__ __align__(16) unsigned short A16[64 * HSTR];   //  9 KB
    __shared__ __align__(16) unsigned short B16[128 * HSTR];  // 18 KB
    const int tid  = threadIdx.x;
    const int lane = tid & 63;
    const int wv   = tid >> 6;
    const int bm = blockIdx.x, bnb = blockIdx.y, s = blockIdx.z;
    const int NST = 241;                       // ceil(15376/64)
    const int c0 = (NST * s) / SPLIT1, c1 = (NST * (s + 1)) / SPLIT1;
    const int mrA = tid & 63, octA = tid >> 6;         // A: row mrA, 16 floats
    const int mrB = tid & 127, octB = (tid >> 7) * 4;  // B: row mrB, 4 octets

    f32x4 acc[8];
    #pragma unroll
    for (int i = 0; i < 8; ++i) acc[i] = (f32x4){0.f, 0.f, 0.f, 0.f};

    float4 a4[4];
    short8 bv[4];
#define LOAD1(cn)                                                              \
    do {                                                                       \
        _Pragma("unroll")                                                      \
        for (int q = 0; q < 4; ++q) {                                          \
            const int k_ = (cn) * 64 + octA * 16 + q * 4;                      \
            a4[q] = (float4){0.f, 0.f, 0.f, 0.f};                              \
            if (k_ + 4 <= FEAT)                                                \
                a4[q] = *(const float4*)&F32[(size_t)(bm * 64 + mrA) * FEAT + k_]; \
        }                                                                      \
        _Pragma("unroll")                                                      \
        for (int q = 0; q < 4; ++q) {                                          \
            const int kB_ = (cn) * 64 + (octB + q) * 8;                        \
            bv[q] = (short8){0, 0, 0, 0, 0, 0, 0, 0};                          \
            if (kB_ + 8 <= FEAT)                                               \
                bv[q] = *(const short8*)&WT1[(size_t)(bnb * 128 + mrB) * FEAT + kB_]; \
        }                                                                      \
    } while (0)

    LOAD1(c0);   // prologue
    for (int ch = c0; ch < c1; ++ch) {
        {
            short8 s0, s1;
            s0[0] = (short)f2bf(a4[0].x); s0[1] = (short)f2bf(a4[0].y);
            s0[2] = (short)f2bf(a4[0].z); s0[3] = (short)f2bf(a4[0].w);
            s0[4] = (short)f2bf(a4[1].x); s0[5] = (short)f2bf(a4[1].y);
            s0[6] = (short)f2bf(a4[1].z); s0[7] = (short)f2bf(a4[1].w);
            s1[0] = (short)f2bf(a4[2].x); s1[1] = (short)f2bf(a4[2].y);
            s1[2] = (short)f2bf(a4[2].z); s1[3] = (short)f2bf(a4[2].w);
            s1[4] = (short)f2bf(a4[3].x); s1[5] = (short)f2bf(a4[3].y);
            s1[6] = (short)f2bf(a4[3].z); s1[7] = (short)f2bf(a4[3].w);
            *(short8*)&A16[mrA * HSTR + octA * 16]     = s0;
            *(short8*)&A16[mrA * HSTR + octA * 16 + 8] = s1;
            #pragma unroll
            for (int q = 0; q < 4; ++q)
                *(short8*)&B16[mrB * HSTR + (octB + q) * 8] = bv[q];
        }
        __syncthreads();
        if (ch + 1 < c1) LOAD1(ch + 1);
        #pragma unroll
        for (int kstp = 0; kstp < 2; ++kstp) {
            short8 af = *(short8*)&A16[(wv * 16 + (lane & 15)) * HSTR
                                       + kstp * 32 + (lane >> 4) * 8];
            #pragma unroll
            for (int nt = 0; nt < 8; ++nt) {
                short8 bf = *(short8*)&B16[(nt * 16 + (lane & 15)) * HSTR
                                           + kstp * 32 + (lane >> 4) * 8];
                acc[nt] = __builtin_amdgcn_mfma_f32_16x16x32_bf16(af, bf, acc[nt], 0, 0, 0);
            }
        }
        __syncthreads();
    }
#undef LOAD1
    const int m0 = bm * 64 + wv * 16 + (lane >> 4) * 4;
    #pragma unroll
    for (int nt = 0; nt < 8; ++nt) {
        int c = bnb * 128 + nt * 16 + (lane & 15);
        #pragma unroll
        for (int rg = 0; rg < 4; ++rg)
            atomicAdd(&H1[(size_t)(m0 + rg) * LIN1 + c], acc[nt][rg]);
    }
}

// ---------------------------------------------------------------------------
// GEMM2 fp32 (split-K=4): H2 += H1[2048,512] @ Wh2.
// ---------------------------------------------------------------------------
#define ACC16(av, bv) do {                              \
    acc[0][0] = fmaf((av).x, (bv).x, acc[0][0]);        \
    acc[0][1] = fmaf((av).x, (bv).y, acc[0][1]);        \
    acc[0][2] = fmaf((av).x, (bv).z, acc[0][2]);        \
    acc[0][3] = fmaf((av).x, (bv).w, acc[0][3]);        \
    acc[1][0] = fmaf((av).y, (bv).x, acc[1][0]);        \
    acc[1][1] = fmaf((av).y, (bv).y, acc[1][1]);        \
    acc[1][2] = fmaf((av).y, (bv).z, acc[1][2]);        \
    acc[1][3] = fmaf((av).y, (bv).w, acc[1][3]);        \
    acc[2][0] = fmaf((av).z, (bv).x, acc[2][0]);        \
    acc[2][1] = fmaf((av).z, (bv).y, acc[2][1]);        \
    acc[2][2] = fmaf((av).z, (bv).z, acc[2][2]);        \
    acc[2][3] = fmaf((av).z, (bv).w, acc[2][3]);        \
    acc[3][0] = fmaf((av).w, (bv).x, acc[3][0]);        \
    acc[3][1] = fmaf((av).w, (bv).y, acc[3][1]);        \
    acc[3][2] = fmaf((av).w, (bv).z, acc[3][2]);        \
    acc[3][3] = fmaf((av).w, (bv).w, acc[3][3]);        \
} while (0)

#define SPLIT2 4
__global__ __launch_bounds__(256) void gemm2_kernel(
    const float* __restrict__ A, const float* __restrict__ B,
    float* __restrict__ C)
{
    __shared__ __align__(16) float As[16 * 72];
    __shared__ __align__(16) float Bs[16 * 64];
    const int bm = blockIdx.x, bnb = blockIdx.y, s = blockIdx.z;
    const int tid = threadIdx.x;
    const int ty4 = (tid >> 4) * 4;
    const int tx4 = (tid & 15) * 4;
    const int kbeg = s * (LIN1 / SPLIT2);
    const int kend = kbeg + LIN1 / SPLIT2;
    float acc[4][4] = {};
    for (int k0 = kbeg; k0 < kend; k0 += 16) {
        for (int i = tid; i < 1024; i += 256) {
            int m = i >> 4, kt = i & 15;
            As[kt * 72 + m] = A[(size_t)(bm * 64 + m) * LIN1 + k0 + kt];
        }
        for (int i = tid; i < 1024; i += 256) {
            int kt = i >> 6, c = i & 63;
            Bs[kt * 64 + c] = B[(size_t)(k0 + kt) * LIN2 + bnb * 64 + c];
        }
        __syncthreads();
        #pragma unroll
        for (int kt = 0; kt < 16; ++kt) {
            const float4 av = *(const float4*)&As[kt * 72 + ty4];
            const float4 bv = *(const float4*)&Bs[kt * 64 + tx4];
            ACC16(av, bv);
        }
        __syncthreads();
    }
    const int b = bm * 64 + ty4, c = bnb * 64 + tx4;
    #pragma unroll
    for (int i = 0; i < 4; ++i)
        #pragma unroll
        for (int j = 0; j < 4; ++j)
            atomicAdd(&C[(size_t)(b + i) * LIN2 + c + j], acc[i][j]);
}

// ---------------------------------------------------------------------------
// BatchNorm (training stats, biased var) + ReLU, in place.
// ---------------------------------------------------------------------------
__global__ __launch_bounds__(256) void bn_relu_kernel(
    float* __restrict__ H, int C,
    const float* __restrict__ gamma, const float* __restrict__ beta)
{
    const int c  = blockIdx.x * 16 + (threadIdx.x & 15);
    const int rt = threadIdx.x >> 4;
    const int ct = threadIdx.x & 15;
    float s = 0.f, s2 = 0.f;
    for (int r = rt; r < BATCH; r += 16) {
        float v = H[(size_t)r * C + c];
        s += v; s2 += v * v;
    }
    __shared__ float Ss[16][16], S2s[16][16], sc_s[16], sh_s[16];
    Ss[rt][ct] = s; S2s[rt][ct] = s2;
    __syncthreads();
    if (rt == 0) {
        float ts = 0.f, ts2 = 0.f;
        #pragma unroll
        for (int i = 0; i < 16; ++i) { ts += Ss[i][ct]; ts2 += S2s[i][ct]; }
        float m   = ts * (1.f / BATCH);
        float var = ts2 * (1.f / BATCH) - m * m;
        float sc  = gamma[c] * rsqrtf(var + BN_EPS);
        sc_s[ct] = sc;
        sh_s[ct] = beta[c] - m * sc;
    }
    __syncthreads();
    const float sc = sc_s[ct], sh = sh_s[ct];
    for (int r = rt; r < BATCH; r += 16) {
        float v = H[(size_t)r * C + c];
        H[(size_t)r * C + c] = fmaxf(fmaf(v, sc, sh), 0.f);
    }
}

// ---------------------------------------------------------------------------
// Final: logits = H2 @ Wh3 + bh3, softmax over 3 classes.
// ---------------------------------------------------------------------------
__global__ __launch_bounds__(256) void final_kernel(
    const float* __restrict__ H2, const float* __restrict__ Wh3,
    const float* __restrict__ bh3, float* __restrict__ out)
{
    __shared__ float Ws[LIN2 * NCLS];
    __shared__ float bs[NCLS];
    const int tid = threadIdx.x;
    for (int i = tid; i < LIN2 * NCLS; i += 256) Ws[i] = Wh3[i];
    if (tid < NCLS) bs[tid] = bh3[tid];
    __syncthreads();
    const int r = blockIdx.x * 256 + tid;
    float a0 = bs[0], a1 = bs[1], a2 = bs[2];
    const float4* row = (const float4*)&H2[(size_t)r * LIN2];
    for (int k4 = 0; k4 < LIN2 / 4; ++k4) {
        float4 h = row[k4];
        int k = k4 * 4;
        a0 = fmaf(h.x, Ws[(k + 0) * 3 + 0], a0);
        a1 = fmaf(h.x, Ws[(k + 0) * 3 + 1], a1);
        a2 = fmaf(h.x, Ws[(k + 0) * 3 + 2], a2);
        a0 = fmaf(h.y, Ws[(k + 1) * 3 + 0], a0);
        a1 = fmaf(h.y, Ws[(k + 1) * 3 + 1], a1);
        a2 = fmaf(h.y, Ws[(k + 1) * 3 + 2], a2);
        a0 = fmaf(h.z, Ws[(k + 2) * 3 + 0], a0);
        a1 = fmaf(h.z, Ws[(k + 2) * 3 + 1], a1);
        a2 = fmaf(h.z, Ws[(k + 2) * 3 + 2], a2);
        a0 = fmaf(h.w, Ws[(k + 3) * 3 + 0], a0);
        a1 = fmaf(h.w, Ws[(k + 3) * 3 + 1], a1);
        a2 = fmaf(h.w, Ws[(k + 3) * 3 + 2], a2);
    }
    float mx = fmaxf(a0, fmaxf(a1, a2));
    float e0 = expf(a0 - mx), e1 = expf(a1 - mx), e2 = expf(a2 - mx);
    float inv = 1.f / (e0 + e1 + e2);
    out[r * 3 + 0] = e0 * inv;
    out[r * 3 + 1] = e1 * inv;
    out[r * 3 + 2] = e2 * inv;
}

// ---------------------------------------------------------------------------
extern "C" void kernel_launch(void* const* d_in, const int* in_sizes, int n_in,
                              void* d_out, int out_size, void* d_ws, size_t ws_size,
                              hipStream_t stream)
{
    const float* x   = (const float*)d_in[0];
    const int*   ei  = (const int*)  d_in[1];
    const float* W1  = (const float*)d_in[2];
    const float* b1  = (const float*)d_in[3];
    const float* W2  = (const float*)d_in[4];
    const float* b2  = (const float*)d_in[5];
    const float* W3  = (const float*)d_in[6];
    const float* b3  = (const float*)d_in[7];
    const float* W4  = (const float*)d_in[8];
    const float* b4  = (const float*)d_in[9];
    const float* Wh1 = (const float*)d_in[10];
    const float* bh1 = (const float*)d_in[11];
    const float* g1  = (const float*)d_in[12];
    const float* be1 = (const float*)d_in[13];
    const float* Wh2 = (const float*)d_in[14];
    const float* bh2 = (const float*)d_in[15];
    const float* g2  = (const float*)d_in[16];
    const float* be2 = (const float*)d_in[17];
    const float* Wh3 = (const float*)d_in[18];
    const float* bh3 = (const float*)d_in[19];
    float* out = (float*)d_out;

    // workspace layout -- TOTAL ~148.7 MB (R10-proven)
    char* ws = (char*)d_ws;
    unsigned short* Tf    = (unsigned short*)(ws + 32768);           // 32768
    unsigned short* WTall = (unsigned short*)(ws + 65536);           // 688128 (4 layers contiguous)
    unsigned short* Wh1T  = (unsigned short*)(ws + 753664);          // 15,745,024
    float* X248 = (float*)(ws + 16498688);                           // 125,960,192
    float* H1   = (float*)(ws + 142458880);                          // 4,194,304
    float* H2   = (float*)(ws + 146653184);                          // 2,097,152

    const int E   = in_sizes[1] / 2;   // 1,015,808
    const int epg = E / BATCH;         // 496 edges of graph 0

    build_LT_convT<<<1, 256, 0, stream>>>(ei, E, epg, Tf);
    conv_wcheb_all<<<dim3(480, 4), 256, 0, stream>>>(W1, W2, W3, W4, WTall);
    transpose_wh1<<<dim3(481, 16), 256, 0, stream>>>(Wh1, Wh1T);

    cheb_fused<<<BATCH, 256, 0, stream>>>(x, X248, WTall, Tf, b1, b2, b3, b4);

    init_bias2<<<(BATCH * (LIN1 + LIN2) / 4 + 255) / 256, 256, 0, stream>>>(H1, bh1, H2, bh2);
    gemm_head1_mfma<<<dim3(32, 4, SPLIT1), 256, 0, stream>>>(X248, Wh1T, H1);
    bn_relu_kernel<<<LIN1 / 16, 256, 0, stream>>>(H1, LIN1, g1, be1);

    gemm2_kernel<<<dim3(32, 4, SPLIT2), 256, 0, stream>>>(H1, Wh2, H2);
    bn_relu_kernel<<<LIN2 / 16, 256, 0, stream>>>(H2, LIN2, g2, be2);

    final_kernel<<<BATCH / 256, 256, 0, stream>>>(H2, Wh3, bh3, out);
}

// Round 13
// 746.344 us; speedup vs baseline: 2.0236x; 2.0236x over previous
//
#include <hip/hip_runtime.h>

// ---------------------------------------------------------------------------
// JointlyTrainModel round 13: REVERT to R10 (measured best, 751 us).
// R12 post-mortem: per-block __threadfence between fused layers = device-scope
// L1 invalidate x 2048 blocks x 3 layers -> permanently cold L1, all staging
// loads become L2 round-trips (MfmaUtil 8%, VALU 9%, HBM 3.5% = pure latency).
// Kernel boundaries (device drain ~10us x3) are far cheaper. Kept from R12:
// merged pre-kernels + merged init_bias (fusion-independent, tiny).
// ---------------------------------------------------------------------------

#define NODES   62
#define BATCH   2048
#define NTOT    (NODES * BATCH)     // 126976
#define IN_DIM  128
#define OUT_DIM 62
#define ACOLS   248                 // 4*62 activation cols
#define FEAT    15376               // 62*248
#define LIN1    512
#define LIN2    256
#define NCLS    3
#define BN_EPS  1e-5f
#define FSTR    36                  // fp32 LDS row stride (floats): 144B rows
#define BSTR    40                  // bf16 LDS row stride in head1 (ushorts)

typedef __attribute__((ext_vector_type(8)))  short  short8;
typedef __attribute__((ext_vector_type(4)))  float  f32x4;
typedef __attribute__((ext_vector_type(16))) float  f32x16;

__device__ inline unsigned short f2bf(float x) {   // RTNE
    unsigned u = __builtin_bit_cast(unsigned, x);
    return (unsigned short)((u + 0x7fffu + ((u >> 16) & 1u)) >> 16);
}
__device__ inline float bf2f(unsigned short h) {
    return __builtin_bit_cast(float, (unsigned)h << 16);
}
// truncation hi/lo split: x ~= hi + lo, |err| ~ 2^-16 |x|
__device__ inline void tsplit(float x, unsigned short& hi, unsigned short& lo) {
    unsigned u = __builtin_bit_cast(unsigned, x);
    hi = (unsigned short)(u >> 16);
    float r = x - __builtin_bit_cast(float, u & 0xffff0000u);
    lo = (unsigned short)(__builtin_bit_cast(unsigned, r) >> 16);
}

// ---------------------------------------------------------------------------
// Build T1 = L~, T2 = 2 L~^2 - I in LDS and emit A-frag-order hi/lo Tf.
// ---------------------------------------------------------------------------
__global__ __launch_bounds__(256) void build_LT_convT(
    const int* __restrict__ ei, int E, int epg, unsigned short* __restrict__ Tf)
{
    __shared__ float Ls[NODES * NODES];
    __shared__ float Ts[2][64 * 64];
    __shared__ int   deg[NODES];
    __shared__ float dinv[NODES];
    const int t = threadIdx.x;
    for (int i = t; i < NODES * NODES; i += 256) Ls[i] = 0.f;
    if (t < NODES) deg[t] = 0;
    __syncthreads();
    const int* row = ei;
    const int* col = ei + E;
    for (int j = t; j < epg; j += 256) atomicAdd(&deg[row[j]], 1);
    __syncthreads();
    if (t < NODES) dinv[t] = (deg[t] > 0) ? rsqrtf((float)deg[t]) : 0.f;
    __syncthreads();
    for (int j = t; j < epg; j += 256) {
        int r = row[j], c = col[j];
        atomicAdd(&Ls[r * NODES + c], -dinv[r] * dinv[c]);
    }
    __syncthreads();
    for (int idx = t; idx < 4096; idx += 256) {
        int r = idx >> 6, c = idx & 63;
        float t1 = 0.f, t2 = 0.f;
        if (r < NODES && c < NODES) {
            t1 = Ls[r * NODES + c];
            float s = 0.f;
            for (int j = 0; j < NODES; ++j) s += Ls[r * NODES + j] * Ls[j * NODES + c];
            t2 = 2.f * s - (r == c ? 1.f : 0.f);
        }
        Ts[0][idx] = t1;
        Ts[1][idx] = t2;
    }
    __syncthreads();
    for (int idx = t; idx < 16384; idx += 256) {
        int j    = idx & 7;
        int lane = (idx >> 3) & 63;
        int pl   = (idx >> 9) & 1;
        int ks   = (idx >> 10) & 3;
        int w    = (idx >> 12) & 3;
        int m = (w & 1) * 32 + (lane & 31);
        int k = ks * 16 + (lane >> 5) * 8 + j;
        float v = Ts[w >> 1][m * 64 + k];
        unsigned short hi, lo;
        tsplit(v, hi, lo);
        Tf[idx] = pl ? lo : hi;
    }
}

// H1 = bh1 broadcast, H2 = bh2 broadcast, one launch.
__global__ __launch_bounds__(256) void init_bias2(
    float* __restrict__ H1, const float* __restrict__ bh1,
    float* __restrict__ H2, const float* __restrict__ bh2)
{
    int i = blockIdx.x * 256 + threadIdx.x;
    const int n1 = BATCH * LIN1 / 4;              // 262144
    if (i < n1) {
        ((float4*)H1)[i] = ((const float4*)bh1)[i & (LIN1 / 4 - 1)];
    } else {
        int j = i - n1;                           // < BATCH*LIN2/4
        ((float4*)H2)[j] = ((const float4*)bh2)[j & (LIN2 / 4 - 1)];
    }
}

// ---------------------------------------------------------------------------
// All 4 cheb weight tensors -> 32x32x16 B-fragment order hi/lo, one launch.
// Outputs contiguous in WTall: chunk-cumulative offsets {0,4,10,18}*12288.
// ---------------------------------------------------------------------------
__global__ __launch_bounds__(256) void conv_wcheb_all(
    const float* __restrict__ W1, const float* __restrict__ W2,
    const float* __restrict__ W3, const float* __restrict__ W4,
    unsigned short* __restrict__ WTall)
{
    const int layer = blockIdx.y;
    const float* W = (layer == 0) ? W1 : (layer == 1) ? W2 : (layer == 2) ? W3 : W4;
    const int d    = (layer == 0) ? 128 : (layer == 1) ? 190 : (layer == 2) ? 252 : 314;
    const int dpad = (layer == 0) ? 128 : (layer == 1) ? 192 : (layer == 2) ? 256 : 320;
    const int cum  = (layer == 0) ? 0 : (layer == 1) ? 4 : (layer == 2) ? 10 : 18;
    unsigned short* WTf = WTall + (size_t)cum * 12288;
    const int total = (dpad >> 5) * 12288;
    int idx = blockIdx.x * 256 + threadIdx.x;
    if (idx >= total) return;
    int j    = idx & 7;
    int lane = (idx >> 3) & 63;
    int f    = idx >> 9;
    int nt   = f & 1;
    int pl   = (f >> 1) & 1;
    int ks   = (f >> 2) & 1;
    int seg  = (f >> 3) % 3;
    int ch   = (f >> 3) / 3;
    int n  = nt * 32 + (lane & 31);
    int kk = ch * 32 + ks * 16 + (lane >> 5) * 8 + j;
    float v = (n < NODES && kk < d) ? W[((size_t)seg * d + kk) * OUT_DIM + n] : 0.f;
    unsigned short hi, lo;
    tsplit(v, hi, lo);
    WTf[idx] = pl ? lo : hi;
}

// ---------------------------------------------------------------------------
// Wh1 [15376][512] fp32 -> Wh1T [512][15376] bf16 via LDS 32x32 transpose.
// ---------------------------------------------------------------------------
__global__ __launch_bounds__(256) void transpose_wh1(
    const float* __restrict__ W, unsigned short* __restrict__ WT)
{
    __shared__ float T[32][33];
    const int k0 = blockIdx.x * 32, n0 = blockIdx.y * 32;
    {
        int kl = threadIdx.x >> 3, n4 = (threadIdx.x & 7) * 4;
        if (k0 + kl < FEAT) {
            float4 v = *(const float4*)&W[(size_t)(k0 + kl) * LIN1 + n0 + n4];
            T[kl][n4] = v.x; T[kl][n4 + 1] = v.y; T[kl][n4 + 2] = v.z; T[kl][n4 + 3] = v.w;
        }
    }
    __syncthreads();
    {
        int nl = threadIdx.x >> 3, k4 = (threadIdx.x & 7) * 4;
        if (k0 + k4 + 3 < FEAT) {
            ushort4 o;
            o.x = f2bf(T[k4 + 0][nl]);
            o.y = f2bf(T[k4 + 1][nl]);
            o.z = f2bf(T[k4 + 2][nl]);
            o.w = f2bf(T[k4 + 3][nl]);
            *(ushort4*)&WT[(size_t)(n0 + nl) * FEAT + k0 + k4] = o;
        }
    }
}

// ---------------------------------------------------------------------------
// Fused Cheb layer (R10/R8 structure, measured best). 3 barriers/chunk,
// register-pipelined loads; dense-T prop in registers via mfma 32x32x16.
// ---------------------------------------------------------------------------
__global__ __launch_bounds__(256, 2) void cheb_mfma(
    const float* __restrict__ x, float* __restrict__ X248,
    const unsigned short* __restrict__ WTf, const unsigned short* __restrict__ Tf,
    const float* __restrict__ bias, int d, int dpad)
{
    __shared__ __align__(16) float hr [64 * FSTR];
    __shared__ __align__(16) float t1r[64 * FSTR];
    __shared__ __align__(16) float t2r[64 * FSTR];
    __shared__ __align__(16) unsigned short hBf[8 * 512];    //  8 KB
    __shared__ __align__(16) unsigned short Bs[24 * 512];    // 24 KB
    __shared__ float bias_s[64];

    const int tid  = threadIdx.x;
    const int g    = blockIdx.x;
    const int lane = tid & 63;
    const int wv   = tid >> 6;

    // permanent T-fragments for this wave: [kstep][plane]
    short8 Tfr[4][2];
    #pragma unroll
    for (int ks = 0; ks < 4; ++ks)
        #pragma unroll
        for (int pl = 0; pl < 2; ++pl)
            Tfr[ks][pl] = *(const short8*)(Tf + (((size_t)(wv * 4 + ks) * 2 + pl) << 9) + lane * 8);

    if (tid < 64) bias_s[tid] = (tid < OUT_DIM) ? bias[tid] : 0.f;

    f32x16 acc;
    #pragma unroll
    for (int i = 0; i < 16; ++i) acc[i] = 0.f;

    const int fcol = tid & 31, rblk = tid >> 5;   // staging map
    const int kst = rblk >> 1, lh = rblk & 1;     // hBf target
    const int nchunk = dpad >> 5;
    const int mtw = wv >> 1, ntw = wv & 1;        // ph4/epilogue tile

#define LOADCH(cn)                                                             \
    do {                                                                       \
        const int gf_ = (cn) * 32 + fcol;                                      \
        const bool fromx_ = ((cn) * 32 < IN_DIM);                              \
        _Pragma("unroll")                                                      \
        for (int p = 0; p < 8; ++p) {                                          \
            int r_ = rblk * 8 + p;                                             \
            float v_ = 0.f;                                                    \
            if (r_ < NODES && gf_ < d)                                         \
                v_ = fromx_ ? x[(size_t)(g * NODES + r_) * IN_DIM + gf_]       \
                            : X248[(size_t)(g * NODES + r_) * ACOLS + (gf_ - IN_DIM)]; \
            vh[p] = v_;                                                        \
        }                                                                      \
        const short8* wsrc_ = (const short8*)(WTf + (size_t)(cn) * 12288);     \
        _Pragma("unroll")                                                      \
        for (int i = 0; i < 6; ++i) breg[i] = wsrc_[i * 256 + tid];            \
    } while (0)

    float  vh[8];
    short8 breg[6];
    LOADCH(0);   // prologue

    for (int ch = 0; ch < nchunk; ++ch) {
        // ---- ph1: write staged data from registers
        {
            short8 hi8, lo8;
            #pragma unroll
            for (int p = 0; p < 8; ++p) {
                unsigned short h_, l_;
                tsplit(vh[p], h_, l_);
                hi8[p] = (short)h_; lo8[p] = (short)l_;
                hr[(rblk * 8 + p) * FSTR + fcol] = vh[p];
            }
            const int dlane = lh * 32 + fcol;
            *(short8*)&hBf[((kst * 2 + 0) << 9) + dlane * 8] = hi8;
            *(short8*)&hBf[((kst * 2 + 1) << 9) + dlane * 8] = lo8;
            #pragma unroll
            for (int i = 0; i < 6; ++i) ((short8*)Bs)[i * 256 + tid] = breg[i];
        }
        __syncthreads();   // A
        // ---- ph3: P = T@h (waves 0,1 -> T1 tiles; 2,3 -> T2 tiles)
        {
            f32x16 pacc;
            #pragma unroll
            for (int i = 0; i < 16; ++i) pacc[i] = 0.f;
            #pragma unroll
            for (int ks = 0; ks < 4; ++ks) {
                short8 bhi = *(const short8*)&hBf[((ks * 2 + 0) << 9) + lane * 8];
                short8 blo = *(const short8*)&hBf[((ks * 2 + 1) << 9) + lane * 8];
                pacc = __builtin_amdgcn_mfma_f32_32x32x16_bf16(Tfr[ks][0], bhi, pacc, 0, 0, 0);
                pacc = __builtin_amdgcn_mfma_f32_32x32x16_bf16(Tfr[ks][0], blo, pacc, 0, 0, 0);
                pacc = __builtin_amdgcn_mfma_f32_32x32x16_bf16(Tfr[ks][1], bhi, pacc, 0, 0, 0);
            }
            float* dst = (wv < 2) ? t1r : t2r;
            const int mbase = (wv & 1) * 32 + 4 * (lane >> 5);
            const int ccol  = lane & 31;
            #pragma unroll
            for (int reg = 0; reg < 16; ++reg) {
                int rr = mbase + (reg & 3) + 8 * (reg >> 2);
                dst[rr * FSTR + ccol] = pacc[reg];
            }
        }
        __syncthreads();   // B
        // ---- ph4: issue next-chunk loads (drain at barrier C), then MFMA
        {
            if (ch + 1 < nchunk) LOADCH(ch + 1);
            #pragma unroll
            for (int seg = 0; seg < 3; ++seg) {
                const float* src = (seg == 0) ? hr : (seg == 1) ? t1r : t2r;
                #pragma unroll
                for (int ks = 0; ks < 2; ++ks) {
                    const int kf = ks * 16 + (lane >> 5) * 8;
                    const float* ap = &src[(mtw * 32 + (lane & 31)) * FSTR + kf];
                    f32x4 u0 = *(const f32x4*)ap;
                    f32x4 u1 = *(const f32x4*)(ap + 4);
                    short8 ahi, alo;
                    #pragma unroll
                    for (int j = 0; j < 4; ++j) {
                        unsigned short h_, l_;
                        tsplit(u0[j], h_, l_); ahi[j] = (short)h_; alo[j] = (short)l_;
                        tsplit(u1[j], h_, l_); ahi[4 + j] = (short)h_; alo[4 + j] = (short)l_;
                    }
                    const unsigned short* bp =
                        Bs + ((((seg * 2 + ks) * 2 + 0) * 2 + ntw) << 9) + lane * 8;
                    short8 bhi = *(const short8*)bp;
                    short8 blo = *(const short8*)(bp + 1024);   // +1 plane = +2 frags
                    acc = __builtin_amdgcn_mfma_f32_32x32x16_bf16(ahi, bhi, acc, 0, 0, 0);
                    acc = __builtin_amdgcn_mfma_f32_32x32x16_bf16(ahi, blo, acc, 0, 0, 0);
                    acc = __builtin_amdgcn_mfma_f32_32x32x16_bf16(alo, bhi, acc, 0, 0, 0);
                }
            }
        }
        __syncthreads();   // C (protects hr/hBf/Bs/t1r/t2r overwrite)
    }
#undef LOADCH
    // epilogue: relu(acc + bias) -> X248[:, (d-128) .. (d-128)+62)
    {
        const int c = ntw * 32 + (lane & 31);
        if (c < OUT_DIM) {
            const int mbase = mtw * 32 + 4 * (lane >> 5);
            #pragma unroll
            for (int reg = 0; reg < 16; ++reg) {
                int m = mbase + (reg & 3) + 8 * (reg >> 2);
                if (m < NODES) {
                    float v = fmaxf(acc[reg] + bias_s[c], 0.f);
                    X248[(size_t)(g * NODES + m) * ACOLS + (d - IN_DIM) + c] = v;
                }
            }
        }
    }
}

// ---------------------------------------------------------------------------
// Head GEMM1 (R10 version, measured <115us): bf16 MFMA, 64x128 tile,
// split-K=8, K=32 stages, register-prefetch pipelined. Grid (32,4,8).
// ---------------------------------------------------------------------------
#define SPLIT1 8
__global__ __launch_bounds__(256) void gemm_head1_mfma(
    const float* __restrict__ F32, const unsigned short* __restrict__ WT1,
    float* __restrict__ H1)
{
    __shared__ __align__(16) unsigned short A16[64 * BSTR];
    __shared__ __align__(16) unsigned short B16[128 * BSTR];
    const int tid  = threadIdx.x;
    const int lane = tid & 63;
    const int wv   = tid >> 6;
    const int bm = blockIdx.x, bnb = blockIdx.y, s = blockIdx.z;
    const int c0 = (481 * s) / SPLIT1, c1 = (481 * (s + 1)) / SPLIT1;
    const int mr = tid >> 2, kg = (tid & 3) * 8;      // A stage map
    const int mrB = tid >> 1, kgB = (tid & 1) * 16;   // B stage map

    f32x4 acc[8];
    #pragma unroll
    for (int i = 0; i < 8; ++i) acc[i] = (f32x4){0.f, 0.f, 0.f, 0.f};

    float4 u0, u1;
    short8 bv0, bv1;
#define LOAD1(cn)                                                              \
    do {                                                                       \
        const int k_ = (cn) * 32 + kg;                                         \
        u0 = (float4){0.f, 0.f, 0.f, 0.f};                                     \
        u1 = (float4){0.f, 0.f, 0.f, 0.f};                                     \
        bv0 = (short8){0, 0, 0, 0, 0, 0, 0, 0};                                \
        bv1 = (short8){0, 0, 0, 0, 0, 0, 0, 0};                                \
        if (k_ + 8 <= FEAT) {                                                  \
            const float4* p_ = (const float4*)&F32[(size_t)(bm * 64 + mr) * FEAT + k_]; \
            u0 = p_[0]; u1 = p_[1];                                            \
        }                                                                      \
        const int kB_ = (cn) * 32 + kgB;                                       \
        if (kB_ + 8 <= FEAT)                                                   \
            bv0 = *(const short8*)&WT1[(size_t)(bnb * 128 + mrB) * FEAT + kB_]; \
        if (kB_ + 16 <= FEAT)                                                  \
            bv1 = *(const short8*)&WT1[(size_t)(bnb * 128 + mrB) * FEAT + kB_ + 8]; \
    } while (0)

    LOAD1(c0);   // prologue
    for (int ch = c0; ch < c1; ++ch) {
        {
            short8 av;
            av[0] = (short)f2bf(u0.x); av[1] = (short)f2bf(u0.y);
            av[2] = (short)f2bf(u0.z); av[3] = (short)f2bf(u0.w);
            av[4] = (short)f2bf(u1.x); av[5] = (short)f2bf(u1.y);
            av[6] = (short)f2bf(u1.z); av[7] = (short)f2bf(u1.w);
            *(short8*)&A16[mr * BSTR + kg] = av;
            *(short8*)&B16[mrB * BSTR + kgB] = bv0;
            *(short8*)&B16[mrB * BSTR + kgB + 8] = bv1;
        }
        __syncthreads();
        if (ch + 1 < c1) LOAD1(ch + 1);
        short8 af = *(short8*)&A16[(wv * 16 + (lane & 15)) * BSTR + (lane >> 4) * 8];
        #pragma unroll
        for (int nt = 0; nt < 8; ++nt) {
            short8 bf = *(short8*)&B16[(nt * 16 + (lane & 15)) * BSTR + (lane >> 4) * 8];
            acc[nt] = __builtin_amdgcn_mfma_f32_16x16x32_bf16(af, bf, acc[nt], 0, 0, 0);
        }
        __syncthreads();
    }
#undef LOAD1
    const int m0 = bm * 64 + wv * 16 + (lane >> 4) * 4;
    #pragma unroll
    for (int nt = 0; nt < 8; ++nt) {
        int c = bnb * 128 + nt * 16 + (lane & 15);
        #pragma unroll
        for (int rg = 0; rg < 4; ++rg)
            atomicAdd(&H1[(size_t)(m0 + rg) * LIN1 + c], acc[nt][rg]);
    }
}

// ---------------------------------------------------------------------------
// GEMM2 fp32 (split-K=4): H2 += H1[2048,512] @ Wh2.
// ---------------------------------------------------------------------------
#define ACC16(av, bv) do {                              \
    acc[0][0] = fmaf((av).x, (bv).x, acc[0][0]);        \
    acc[0][1] = fmaf((av).x, (bv).y, acc[0][1]);        \
    acc[0][2] = fmaf((av).x, (bv).z, acc[0][2]);        \
    acc[0][3] = fmaf((av).x, (bv).w, acc[0][3]);        \
    acc[1][0] = fmaf((av).y, (bv).x, acc[1][0]);        \
    acc[1][1] = fmaf((av).y, (bv).y, acc[1][1]);        \
    acc[1][2] = fmaf((av).y, (bv).z, acc[1][2]);        \
    acc[1][3] = fmaf((av).y, (bv).w, acc[1][3]);        \
    acc[2][0] = fmaf((av).z, (bv).x, acc[2][0]);        \
    acc[2][1] = fmaf((av).z, (bv).y, acc[2][1]);        \
    acc[2][2] = fmaf((av).z, (bv).z, acc[2][2]);        \
    acc[2][3] = fmaf((av).z, (bv).w, acc[2][3]);        \
    acc[3][0] = fmaf((av).w, (bv).x, acc[3][0]);        \
    acc[3][1] = fmaf((av).w, (bv).y, acc[3][1]);        \
    acc[3][2] = fmaf((av).w, (bv).z, acc[3][2]);        \
    acc[3][3] = fmaf((av).w, (bv).w, acc[3][3]);        \
} while (0)

#define SPLIT2 4
__global__ __launch_bounds__(256) void gemm2_kernel(
    const float* __restrict__ A, const float* __restrict__ B,
    float* __restrict__ C)
{
    __shared__ __align__(16) float As[16 * 72];
    __shared__ __align__(16) float Bs[16 * 64];
    const int bm = blockIdx.x, bnb = blockIdx.y, s = blockIdx.z;
    const int tid = threadIdx.x;
    const int ty4 = (tid >> 4) * 4;
    const int tx4 = (tid & 15) * 4;
    const int kbeg = s * (LIN1 / SPLIT2);
    const int kend = kbeg + LIN1 / SPLIT2;
    float acc[4][4] = {};
    for (int k0 = kbeg; k0 < kend; k0 += 16) {
        for (int i = tid; i < 1024; i += 256) {
            int m = i >> 4, kt = i & 15;
            As[kt * 72 + m] = A[(size_t)(bm * 64 + m) * LIN1 + k0 + kt];
        }
        for (int i = tid; i < 1024; i += 256) {
            int kt = i >> 6, c = i & 63;
            Bs[kt * 64 + c] = B[(size_t)(k0 + kt) * LIN2 + bnb * 64 + c];
        }
        __syncthreads();
        #pragma unroll
        for (int kt = 0; kt < 16; ++kt) {
            const float4 av = *(const float4*)&As[kt * 72 + ty4];
            const float4 bv = *(const float4*)&Bs[kt * 64 + tx4];
            ACC16(av, bv);
        }
        __syncthreads();
    }
    const int b = bm * 64 + ty4, c = bnb * 64 + tx4;
    #pragma unroll
    for (int i = 0; i < 4; ++i)
        #pragma unroll
        for (int j = 0; j < 4; ++j)
            atomicAdd(&C[(size_t)(b + i) * LIN2 + c + j], acc[i][j]);
}

// ---------------------------------------------------------------------------
// BatchNorm (training stats, biased var) + ReLU, in place.
// ---------------------------------------------------------------------------
__global__ __launch_bounds__(256) void bn_relu_kernel(
    float* __restrict__ H, int C,
    const float* __restrict__ gamma, const float* __restrict__ beta)
{
    const int c  = blockIdx.x * 16 + (threadIdx.x & 15);
    const int rt = threadIdx.x >> 4;
    const int ct = threadIdx.x & 15;
    float s = 0.f, s2 = 0.f;
    for (int r = rt; r < BATCH; r += 16) {
        float v = H[(size_t)r * C + c];
        s += v; s2 += v * v;
    }
    __shared__ float Ss[16][16], S2s[16][16], sc_s[16], sh_s[16];
    Ss[rt][ct] = s; S2s[rt][ct] = s2;
    __syncthreads();
    if (rt == 0) {
        float ts = 0.f, ts2 = 0.f;
        #pragma unroll
        for (int i = 0; i < 16; ++i) { ts += Ss[i][ct]; ts2 += S2s[i][ct]; }
        float m   = ts * (1.f / BATCH);
        float var = ts2 * (1.f / BATCH) - m * m;
        float sc  = gamma[c] * rsqrtf(var + BN_EPS);
        sc_s[ct] = sc;
        sh_s[ct] = beta[c] - m * sc;
    }
    __syncthreads();
    const float sc = sc_s[ct], sh = sh_s[ct];
    for (int r = rt; r < BATCH; r += 16) {
        float v = H[(size_t)r * C + c];
        H[(size_t)r * C + c] = fmaxf(fmaf(v, sc, sh), 0.f);
    }
}

// ---------------------------------------------------------------------------
// Final: logits = H2 @ Wh3 + bh3, softmax over 3 classes.
// ---------------------------------------------------------------------------
__global__ __launch_bounds__(256) void final_kernel(
    const float* __restrict__ H2, const float* __restrict__ Wh3,
    const float* __restrict__ bh3, float* __restrict__ out)
{
    __shared__ float Ws[LIN2 * NCLS];
    __shared__ float bs[NCLS];
    const int tid = threadIdx.x;
    for (int i = tid; i < LIN2 * NCLS; i += 256) Ws[i] = Wh3[i];
    if (tid < NCLS) bs[tid] = bh3[tid];
    __syncthreads();
    const int r = blockIdx.x * 256 + tid;
    float a0 = bs[0], a1 = bs[1], a2 = bs[2];
    const float4* row = (const float4*)&H2[(size_t)r * LIN2];
    for (int k4 = 0; k4 < LIN2 / 4; ++k4) {
        float4 h = row[k4];
        int k = k4 * 4;
        a0 = fmaf(h.x, Ws[(k + 0) * 3 + 0], a0);
        a1 = fmaf(h.x, Ws[(k + 0) * 3 + 1], a1);
        a2 = fmaf(h.x, Ws[(k + 0) * 3 + 2], a2);
        a0 = fmaf(h.y, Ws[(k + 1) * 3 + 0], a0);
        a1 = fmaf(h.y, Ws[(k + 1) * 3 + 1], a1);
        a2 = fmaf(h.y, Ws[(k + 1) * 3 + 2], a2);
        a0 = fmaf(h.z, Ws[(k + 2) * 3 + 0], a0);
        a1 = fmaf(h.z, Ws[(k + 2) * 3 + 1], a1);
        a2 = fmaf(h.z, Ws[(k + 2) * 3 + 2], a2);
        a0 = fmaf(h.w, Ws[(k + 3) * 3 + 0], a0);
        a1 = fmaf(h.w, Ws[(k + 3) * 3 + 1], a1);
        a2 = fmaf(h.w, Ws[(k + 3) * 3 + 2], a2);
    }
    float mx = fmaxf(a0, fmaxf(a1, a2));
    float e0 = expf(a0 - mx), e1 = expf(a1 - mx), e2 = expf(a2 - mx);
    float inv = 1.f / (e0 + e1 + e2);
    out[r * 3 + 0] = e0 * inv;
    out[r * 3 + 1] = e1 * inv;
    out[r * 3 + 2] = e2 * inv;
}

// ---------------------------------------------------------------------------
extern "C" void kernel_launch(void* const* d_in, const int* in_sizes, int n_in,
                              void* d_out, int out_size, void* d_ws, size_t ws_size,
                              hipStream_t stream)
{
    const float* x   = (const float*)d_in[0];
    const int*   ei  = (const int*)  d_in[1];
    const float* W1  = (const float*)d_in[2];
    const float* b1  = (const float*)d_in[3];
    const float* W2  = (const float*)d_in[4];
    const float* b2  = (const float*)d_in[5];
    const float* W3  = (const float*)d_in[6];
    const float* b3  = (const float*)d_in[7];
    const float* W4  = (const float*)d_in[8];
    const float* b4  = (const float*)d_in[9];
    const float* Wh1 = (const float*)d_in[10];
    const float* bh1 = (const float*)d_in[11];
    const float* g1  = (const float*)d_in[12];
    const float* be1 = (const float*)d_in[13];
    const float* Wh2 = (const float*)d_in[14];
    const float* bh2 = (const float*)d_in[15];
    const float* g2  = (const float*)d_in[16];
    const float* be2 = (const float*)d_in[17];
    const float* Wh3 = (const float*)d_in[18];
    const float* bh3 = (const float*)d_in[19];
    float* out = (float*)d_out;

    // workspace layout -- TOTAL ~148.7 MB (R10-proven)
    char* ws = (char*)d_ws;
    unsigned short* Tf    = (unsigned short*)(ws + 32768);           // 32768
    unsigned short* WTall = (unsigned short*)(ws + 65536);           // 688128 (4 layers contiguous)
    unsigned short* Wh1T  = (unsigned short*)(ws + 753664);          // 15,745,024
    float* X248 = (float*)(ws + 16498688);                           // 125,960,192
    float* H1   = (float*)(ws + 142458880);                          // 4,194,304
    float* H2   = (float*)(ws + 146653184);                          // 2,097,152

    const int E   = in_sizes[1] / 2;   // 1,015,808
    const int epg = E / BATCH;         // 496 edges of graph 0

    build_LT_convT<<<1, 256, 0, stream>>>(ei, E, epg, Tf);
    conv_wcheb_all<<<dim3(480, 4), 256, 0, stream>>>(W1, W2, W3, W4, WTall);
    transpose_wh1<<<dim3(481, 16), 256, 0, stream>>>(Wh1, Wh1T);

    cheb_mfma<<<BATCH, 256, 0, stream>>>(x, X248, WTall + (size_t)0 * 12288,  Tf, b1, 128, 128);
    cheb_mfma<<<BATCH, 256, 0, stream>>>(x, X248, WTall + (size_t)4 * 12288,  Tf, b2, 190, 192);
    cheb_mfma<<<BATCH, 256, 0, stream>>>(x, X248, WTall + (size_t)10 * 12288, Tf, b3, 252, 256);
    cheb_mfma<<<BATCH, 256, 0, stream>>>(x, X248, WTall + (size_t)18 * 12288, Tf, b4, 314, 320);

    init_bias2<<<(BATCH * (LIN1 + LIN2) / 4 + 255) / 256, 256, 0, stream>>>(H1, bh1, H2, bh2);
    gemm_head1_mfma<<<dim3(32, 4, SPLIT1), 256, 0, stream>>>(X248, Wh1T, H1);
    bn_relu_kernel<<<LIN1 / 16, 256, 0, stream>>>(H1, LIN1, g1, be1);

    gemm2_kernel<<<dim3(32, 4, SPLIT2), 256, 0, stream>>>(H1, Wh2, H2);
    bn_relu_kernel<<<LIN2 / 16, 256, 0, stream>>>(H2, LIN2, g2, be2);

    final_kernel<<<BATCH / 256, 256, 0, stream>>>(H2, Wh3, bh3, out);
}